// Round 9
// baseline (165.299 us; speedup 1.0000x reference)
//
#include <hip/hip_runtime.h>

#define FEAT_IN  500
#define FEAT_OUT 7
#define NXCD     8
#define OVF_CAP  65536

// ---- r9 params (r7/r8 structure) ----
#define RNG     512            // nodes per coarse bucket
#define LG      9              // log2(RNG)
#define PART_NB 208            // compile-time bucket cap for part7 LDS stages
#define NBLK    1024           // partition blocks
#define SLOT    32             // LDS stage slots per (block,bucket)
#define CH_S    8              // srccount chunks per bucket
#define CHA     8              // accum chunks per bucket
#define SLABN   16             // slab entries per (node,chunk)
#define SLABS   17             // slab stride (odd: bank-conflict-free)
#define OVF7    (1 << 22)      // >= E: exact even under full skew

// ============================================================================
// PRIMARY PATH r9 = r8 (verified 163.9us) + launch/pass fusion:
//  - red7 folded into feat (lane0 sums 8 chunk-histograms + loopcnt inline)
//  - ovf_s adds into outcnt_c[0][s] (== index s exactly), not a separate pass
//  - part7 inner loop 2-edge unrolled
// Model: LDS atomics ~3.7 cyc/lane, 4/edge across part/scount/accum = ~80us
// floor; feat HBM floor ~33us; everything else is launch/pass overhead.
// ============================================================================

__global__ void init7_kernel(unsigned long long* __restrict__ gcur,
                             unsigned* __restrict__ loopcnt, unsigned* __restrict__ ovfc,
                             int nb, int cap, int n) {
    int i = blockIdx.x * blockDim.x + threadIdx.x;
    if (i < nb) {
        unsigned long long v = (unsigned long long)(unsigned)(i * cap);
        gcur[i] = (v << 32) | v;   // hi: src cursor, lo: dst cursor (dense-exact)
    }
    if (i < n) loopcnt[i] = 0;
    if (i < 16) ovfc[i] = 0;
}

// P1 (r7-verified): LDS-staged, line-coalesced dense-exact partition, both
// sides; 1 returning LDS atomic + 1 LDS write per side; one u64 global atomic
// per (block,bucket); self-loops -> loopcnt (analytic path). 2-edge unroll.
__global__ void part7_kernel(const int* __restrict__ src, const int* __restrict__ dst,
                             unsigned long long* __restrict__ gcur,
                             unsigned* __restrict__ dstpart, unsigned short* __restrict__ srcpart,
                             unsigned* __restrict__ loopcnt,
                             unsigned* __restrict__ ovfc, unsigned* __restrict__ ovf_d,
                             unsigned* __restrict__ ovf_s, int E, int nb, int cap) {
    __shared__ unsigned cnt_d[PART_NB], cnt_s[PART_NB];
    __shared__ unsigned base_d[PART_NB], base_s[PART_NB];
    __shared__ unsigned dstage[PART_NB * (SLOT + 1)];
    __shared__ unsigned short sstage[PART_NB * SLOT];

    int chunk = (E + gridDim.x - 1) / gridDim.x;
    int e0 = blockIdx.x * chunk, e1 = min(e0 + chunk, E);
    for (int i = threadIdx.x; i < nb; i += blockDim.x) { cnt_d[i] = 0; cnt_s[i] = 0; }
    __syncthreads();

    for (int e = e0 + threadIdx.x * 2; e < e1; e += blockDim.x * 2) {
        #pragma unroll
        for (int u = 0; u < 2; ++u) {
            int ee = e + u;
            if (ee >= e1) break;
            int s = src[ee], d = dst[ee];
            if (s == d) { atomicAdd(&loopcnt[s], 1u); continue; }
            int bd = d >> LG;
            unsigned pd = atomicAdd(&cnt_d[bd], 1u);
            if (pd < (unsigned)SLOT) {
                dstage[bd * (SLOT + 1) + pd] = ((unsigned)(d & (RNG - 1)) << 17) | (unsigned)s;
            } else {
                unsigned o = atomicAdd(&ovfc[0], 1u);
                if (o < (unsigned)OVF7) { ovf_d[2 * o] = (unsigned)s; ovf_d[2 * o + 1] = (unsigned)d; }
            }
            int bs = s >> LG;
            unsigned ps = atomicAdd(&cnt_s[bs], 1u);
            if (ps < (unsigned)SLOT) {
                sstage[bs * SLOT + ps] = (unsigned short)(s & (RNG - 1));
            } else {
                unsigned o = atomicAdd(&ovfc[1], 1u);
                if (o < (unsigned)OVF7) ovf_s[o] = (unsigned)s;
            }
        }
    }
    __syncthreads();

    for (int i = threadIdx.x; i < nb; i += blockDim.x) {
        unsigned cd = min(cnt_d[i], (unsigned)SLOT);
        unsigned cs = min(cnt_s[i], (unsigned)SLOT);
        cnt_d[i] = cd; cnt_s[i] = cs;
        unsigned long long old = atomicAdd(&gcur[i],
            ((unsigned long long)cs << 32) | (unsigned long long)cd);
        base_d[i] = (unsigned)old;
        base_s[i] = (unsigned)(old >> 32);
    }
    __syncthreads();

    int grp = threadIdx.x >> 5, lk = threadIdx.x & 31;
    for (int i = grp; i < nb; i += 8) {
        if ((unsigned)lk < cnt_d[i]) {
            unsigned gidx = base_d[i] + (unsigned)lk;
            unsigned pk = dstage[i * (SLOT + 1) + lk];
            if (gidx < (unsigned)((i + 1) * cap)) dstpart[gidx] = pk;
            else {
                unsigned o = atomicAdd(&ovfc[0], 1u);
                if (o < (unsigned)OVF7) { ovf_d[2 * o] = pk & 0x1FFFFu; ovf_d[2 * o + 1] = (unsigned)(i * RNG) + (pk >> 17); }
            }
        }
        if ((unsigned)lk < cnt_s[i]) {
            unsigned gidx = base_s[i] + (unsigned)lk;
            unsigned short sl = sstage[i * SLOT + lk];
            if (gidx < (unsigned)((i + 1) * cap)) srcpart[gidx] = sl;
            else {
                unsigned o = atomicAdd(&ovfc[1], 1u);
                if (o < (unsigned)OVF7) ovf_s[o] = (unsigned)(i * RNG) + (unsigned)sl;
            }
        }
    }
}

// P2b (r7-verified): chunked out-degree histogram over dense srcpart runs.
__global__ void srccount_kernel(const unsigned long long* __restrict__ gcur,
                                const unsigned short* __restrict__ srcpart,
                                unsigned* __restrict__ outcnt_c, int cap, int npad, int chs) {
    int b = blockIdx.x / chs, ch = blockIdx.x % chs;
    __shared__ unsigned hist[RNG];
    hist[threadIdx.x] = 0;
    hist[threadIdx.x + 256] = 0;
    __syncthreads();
    unsigned base = (unsigned)b * (unsigned)cap;
    unsigned tot = (unsigned)(gcur[b] >> 32) - base;
    unsigned scnt = tot < (unsigned)cap ? tot : (unsigned)cap;
    unsigned clen = (scnt + (unsigned)chs - 1) / (unsigned)chs;
    unsigned i0 = (unsigned)ch * clen;
    unsigned i1 = i0 + clen; if (i1 > scnt) i1 = scnt;
    for (unsigned i = i0 + threadIdx.x; i < i1; i += blockDim.x)
        atomicAdd(&hist[srcpart[base + i]], 1u);
    __syncthreads();
    unsigned* oc = outcnt_c + (size_t)ch * npad + (size_t)b * RNG;
    oc[threadIdx.x] = hist[threadIdx.x];
    oc[threadIdx.x + 256] = hist[threadIdx.x + 256];
}

// src-overflow degrees: add into chunk-0 histogram slice; index b*RNG+local == s.
// Launch-ordered AFTER srccount's plain stores, BEFORE feat.
__global__ void ovf_s9_kernel(const unsigned* __restrict__ ovfc, const unsigned* __restrict__ ovf_s,
                              unsigned* __restrict__ outcnt_c) {
    unsigned c = ovfc[1]; if (c > (unsigned)OVF7) c = (unsigned)OVF7;
    unsigned stride = gridDim.x * blockDim.x;
    for (unsigned i = blockIdx.x * blockDim.x + threadIdx.x; i < c; i += stride)
        atomicAdd(&outcnt_c[ovf_s[i]], 1u);
}

// K-feat r9: feat = (h @ W) * rsqrt(max(outdeg,1)); W in VGPRs (r8-verified);
// outdeg computed inline (red7 fused): loopcnt + sum of 8 chunk histograms.
__global__ void feat_kernel9(const float* __restrict__ h, const float* __restrict__ W,
                             const unsigned* __restrict__ outcnt_c,
                             const unsigned* __restrict__ loopcnt,
                             float* __restrict__ feat, int n, int npad) {
    __shared__ float Wt[FEAT_OUT * FEAT_IN];  // 14 KB, transposed (built once)
    for (int k = threadIdx.x; k < FEAT_IN; k += blockDim.x) {
        #pragma unroll
        for (int j = 0; j < FEAT_OUT; ++j) Wt[j * FEAT_IN + k] = W[k * FEAT_OUT + j];
    }
    __syncthreads();

    const int lane   = threadIdx.x & 63;
    const int wid    = (blockIdx.x * blockDim.x + threadIdx.x) >> 6;
    const int nwaves = (gridDim.x * blockDim.x) >> 6;
    const float4* Wt4 = (const float4*)Wt;  // Wt4[j*125 + v]

    float4 wreg[2][FEAT_OUT];
    #pragma unroll
    for (int it = 0; it < 2; ++it) {
        int v = it * 64 + lane;
        #pragma unroll
        for (int j = 0; j < FEAT_OUT; ++j)
            wreg[it][j] = (v < 125) ? Wt4[j * 125 + v] : make_float4(0.f, 0.f, 0.f, 0.f);
    }

    for (int i = wid; i < n; i += nwaves) {
        const float4* hv = (const float4*)(h + (size_t)i * FEAT_IN);  // 125 float4s
        float acc[FEAT_OUT] = {0, 0, 0, 0, 0, 0, 0};
        #pragma unroll
        for (int it = 0; it < 2; ++it) {
            int v = it * 64 + lane;
            if (v < 125) {
                float4 x = hv[v];
                #pragma unroll
                for (int j = 0; j < FEAT_OUT; ++j) {
                    float4 w = wreg[it][j];
                    acc[j] += x.x * w.x + x.y * w.y + x.z * w.z + x.w * w.w;
                }
            }
        }
        #pragma unroll
        for (int j = 0; j < FEAT_OUT; ++j) {
            #pragma unroll
            for (int o = 32; o > 0; o >>= 1) acc[j] += __shfl_xor(acc[j], o, 64);
        }
        if (lane == 0) {
            unsigned deg = loopcnt[i];
            #pragma unroll
            for (int c = 0; c < CH_S; ++c) deg += outcnt_c[(size_t)c * npad + i];
            float nrm = rsqrtf(fmaxf((float)deg, 1.0f));
            float4* fo = (float4*)(feat + (size_t)i * 8);
            fo[0] = make_float4(acc[0] * nrm, acc[1] * nrm, acc[2] * nrm, acc[3] * nrm);
            fo[1] = make_float4(acc[4] * nrm, acc[5] * nrm, acc[6] * nrm, 0.f);
        }
    }
}

// P2a (r7-verified): slab accumulate, 1 LDS atomic/record, register reduce.
__global__ void accum3_kernel(const unsigned long long* __restrict__ gcur,
                              const unsigned* __restrict__ dstpart,
                              const float* __restrict__ feat,
                              float* __restrict__ accf_c,
                              unsigned* __restrict__ ovfc, unsigned* __restrict__ ovf_d,
                              int cap, int npad, int cha) {
    int b = blockIdx.x / cha, ch = blockIdx.x % cha;
    __shared__ unsigned slab[RNG * SLABS];   // 34.8 KB
    __shared__ unsigned cur[RNG];
    cur[threadIdx.x] = 0;                    // blockDim == RNG == 512
    __syncthreads();
    unsigned base = (unsigned)b * (unsigned)cap;
    unsigned tot = (unsigned)(gcur[b] & 0xffffffffu) - base;
    unsigned ecnt = tot < (unsigned)cap ? tot : (unsigned)cap;
    unsigned clen = (ecnt + (unsigned)cha - 1) / (unsigned)cha;
    unsigned i0 = (unsigned)ch * clen;
    unsigned i1 = i0 + clen; if (i1 > ecnt) i1 = ecnt;
    for (unsigned i = i0 + threadIdx.x; i < i1; i += blockDim.x) {
        unsigned pk = dstpart[base + i];
        unsigned dl = pk >> 17;
        unsigned p = atomicAdd(&cur[dl], 1u);
        if (p < (unsigned)SLABN) {
            slab[dl * SLABS + p] = pk & 0x1FFFFu;
        } else {
            unsigned o = atomicAdd(&ovfc[0], 1u);
            if (o < (unsigned)OVF7) { ovf_d[2 * o] = pk & 0x1FFFFu; ovf_d[2 * o + 1] = (unsigned)b * RNG + dl; }
        }
    }
    __syncthreads();
    int t = threadIdx.x;
    unsigned cnt = cur[t]; if (cnt > (unsigned)SLABN) cnt = (unsigned)SLABN;
    float a0 = 0, a1 = 0, a2 = 0, a3 = 0, a4 = 0, a5 = 0, a6 = 0;
    const unsigned* sl = slab + t * SLABS;
    for (unsigned k = 0; k < cnt; ++k) {
        const float4* f = (const float4*)(feat + (size_t)sl[k] * 8);
        float4 x = f[0], y = f[1];
        a0 += x.x; a1 += x.y; a2 += x.z; a3 += x.w;
        a4 += y.x; a5 += y.y; a6 += y.z;
    }
    float4* dstp = (float4*)(accf_c + (size_t)ch * npad * 8 + ((size_t)b * RNG + t) * 8);
    dstp[0] = make_float4(a0, a1, a2, a3);
    dstp[1] = make_float4(a4, a5, a6, (float)cnt);
}

__global__ void ovf_d7_kernel(const unsigned* __restrict__ ovfc, const unsigned* __restrict__ ovf_d,
                              const float* __restrict__ feat, float* __restrict__ accf_c) {
    unsigned c = ovfc[0]; if (c > (unsigned)OVF7) c = (unsigned)OVF7;
    unsigned stride = gridDim.x * blockDim.x;
    for (unsigned i = blockIdx.x * blockDim.x + threadIdx.x; i < c; i += stride) {
        unsigned s = ovf_d[2 * i], d = ovf_d[2 * i + 1];
        const float* f = feat + (size_t)s * 8;
        float* p = accf_c + (size_t)d * 8;
        #pragma unroll
        for (int j = 0; j < FEAT_OUT; ++j) atomicAdd(p + j, f[j]);
        atomicAdd(p + 7, 1.0f);
    }
}

__global__ void final7_kernel(const float* __restrict__ accf_c, const float* __restrict__ feat,
                              const unsigned* __restrict__ loopcnt, const float* __restrict__ b,
                              float* __restrict__ out, int n, int npad) {
    int i = blockIdx.x * blockDim.x + threadIdx.x;
    if (i >= n) return;
    float s0 = 0, s1 = 0, s2 = 0, s3 = 0, s4 = 0, s5 = 0, s6 = 0, s7 = 0;
    #pragma unroll
    for (int c = 0; c < CHA; ++c) {
        const float4* p = (const float4*)(accf_c + (size_t)c * npad * 8 + (size_t)i * 8);
        float4 a = p[0], d = p[1];
        s0 += a.x; s1 += a.y; s2 += a.z; s3 += a.w;
        s4 += d.x; s5 += d.y; s6 += d.z; s7 += d.w;
    }
    float lc = (float)loopcnt[i];
    const float4* f = (const float4*)(feat + (size_t)i * 8);
    float4 fa = f[0], fb = f[1];
    s0 += lc * fa.x; s1 += lc * fa.y; s2 += lc * fa.z; s3 += lc * fa.w;
    s4 += lc * fb.x; s5 += lc * fb.y; s6 += lc * fb.z; s7 += lc;
    float nin = rsqrtf(fmaxf(s7, 1.0f));
    float* o = out + (size_t)i * FEAT_OUT;
    o[0] = s0 * nin + b[0]; o[1] = s1 * nin + b[1]; o[2] = s2 * nin + b[2];
    o[3] = s3 * nin + b[3]; o[4] = s4 * nin + b[4]; o[5] = s5 * nin + b[5];
    o[6] = s6 * nin + b[6];
}

// ============================================================================
// SECONDARY PATH (round-1 verified): per-edge counting-sort buckets + gather.
// ============================================================================

__global__ void feat_kernel2(const float* __restrict__ h, const float* __restrict__ W,
                             const unsigned* __restrict__ outcnt,
                             float* __restrict__ feat, int n) {
    __shared__ float Wt[FEAT_OUT * FEAT_IN];
    for (int k = threadIdx.x; k < FEAT_IN; k += blockDim.x) {
        #pragma unroll
        for (int j = 0; j < FEAT_OUT; ++j) Wt[j * FEAT_IN + k] = W[k * FEAT_OUT + j];
    }
    __syncthreads();
    const int lane   = threadIdx.x & 63;
    const int wid    = (blockIdx.x * blockDim.x + threadIdx.x) >> 6;
    const int nwaves = (gridDim.x * blockDim.x) >> 6;
    const float4* Wt4 = (const float4*)Wt;
    for (int i = wid; i < n; i += nwaves) {
        const float4* hv = (const float4*)(h + (size_t)i * FEAT_IN);
        float acc[FEAT_OUT] = {0, 0, 0, 0, 0, 0, 0};
        #pragma unroll
        for (int it = 0; it < 2; ++it) {
            int v = it * 64 + lane;
            if (v < 125) {
                float4 x = hv[v];
                #pragma unroll
                for (int j = 0; j < FEAT_OUT; ++j) {
                    float4 w = Wt4[j * 125 + v];
                    acc[j] += x.x * w.x + x.y * w.y + x.z * w.z + x.w * w.w;
                }
            }
        }
        #pragma unroll
        for (int j = 0; j < FEAT_OUT; ++j) {
            #pragma unroll
            for (int o = 32; o > 0; o >>= 1) acc[j] += __shfl_xor(acc[j], o, 64);
        }
        if (lane == 0) {
            float nrm = rsqrtf(fmaxf((float)outcnt[i], 1.0f));
            float* fo = feat + (size_t)i * 8;
            #pragma unroll
            for (int j = 0; j < FEAT_OUT; ++j) fo[j] = acc[j] * nrm;
        }
    }
}

__global__ void count_scatter_kernel(const int* __restrict__ src, const int* __restrict__ dst,
                                     unsigned* __restrict__ cursor, unsigned* __restrict__ outcnt,
                                     unsigned* __restrict__ bucket, unsigned* __restrict__ ovfcnt,
                                     unsigned* __restrict__ ovf, int E, int cap) {
    int stride = gridDim.x * blockDim.x;
    for (int e = blockIdx.x * blockDim.x + threadIdx.x; e < E; e += stride) {
        int s = src[e], d = dst[e];
        atomicAdd(&outcnt[s], 1u);
        unsigned pos = atomicAdd(&cursor[d], 1u);
        if (pos < (unsigned)cap) {
            bucket[(size_t)d * cap + pos] = (unsigned)s;
        } else {
            unsigned o = atomicAdd(ovfcnt, 1u);
            if (o < OVF_CAP) { ovf[2 * o] = (unsigned)s; ovf[2 * o + 1] = (unsigned)d; }
        }
    }
}

__global__ void gather_kernel(const unsigned* __restrict__ cursor, const unsigned* __restrict__ bucket,
                              const float* __restrict__ feat, const float* __restrict__ b,
                              float* __restrict__ out, int n, int cap) {
    int t   = blockIdx.x * blockDim.x + threadIdx.x;
    int gid = t >> 3;
    int l   = t & 7;
    if (gid >= n) return;
    unsigned full = cursor[gid];
    int cnt = (int)(full < (unsigned)cap ? full : (unsigned)cap);
    const unsigned* bk = bucket + (size_t)gid * cap;
    float acc[FEAT_OUT] = {0, 0, 0, 0, 0, 0, 0};
    for (int e = l; e < cnt; e += 8) {
        unsigned s = bk[e];
        const float4* f = (const float4*)(feat + (size_t)s * 8);
        float4 a = f[0];
        float4 c = f[1];
        acc[0] += a.x; acc[1] += a.y; acc[2] += a.z; acc[3] += a.w;
        acc[4] += c.x; acc[5] += c.y; acc[6] += c.z;
    }
    #pragma unroll
    for (int j = 0; j < FEAT_OUT; ++j) {
        acc[j] += __shfl_xor(acc[j], 1, 64);
        acc[j] += __shfl_xor(acc[j], 2, 64);
        acc[j] += __shfl_xor(acc[j], 4, 64);
    }
    if (l == 0) {
        float nin = rsqrtf(fmaxf((float)full, 1.0f));
        float* o = out + (size_t)gid * FEAT_OUT;
        #pragma unroll
        for (int j = 0; j < FEAT_OUT; ++j) o[j] = acc[j] * nin + b[j];
    }
}

__global__ void ovf_kernel(const unsigned* __restrict__ ovfcnt, const unsigned* __restrict__ ovf,
                           const float* __restrict__ feat, const unsigned* __restrict__ cursor,
                           float* __restrict__ out) {
    unsigned c = ovfcnt[0];
    if (c > OVF_CAP) c = OVF_CAP;
    unsigned stride = gridDim.x * blockDim.x;
    for (unsigned i = blockIdx.x * blockDim.x + threadIdx.x; i < c; i += stride) {
        unsigned s = ovf[2 * i], d = ovf[2 * i + 1];
        float nin = rsqrtf(fmaxf((float)cursor[d], 1.0f));
        const float* f = feat + (size_t)s * 8;
        #pragma unroll
        for (int j = 0; j < FEAT_OUT; ++j)
            atomicAdd(&out[(size_t)d * FEAT_OUT + j], f[j] * nin);
    }
}

// ============================================================================

extern "C" void kernel_launch(void* const* d_in, const int* in_sizes, int n_in,
                              void* d_out, int out_size, void* d_ws, size_t ws_size,
                              hipStream_t stream) {
    const float* h   = (const float*)d_in[0];
    const float* W   = (const float*)d_in[1];
    const float* b   = (const float*)d_in[2];
    const int*   src = (const int*)d_in[3];
    const int*   dst = (const int*)d_in[4];

    const int n = in_sizes[0] / FEAT_IN;   // 100000
    const int E = in_sizes[3];             // 3300000
    float* out = (float*)d_out;

    // ---------------- primary: r9 path ----------------
    int nb = (n + RNG - 1) / RNG;          // 196
    if (nb >= 2 && nb <= PART_NB) {
        size_t npad = (size_t)nb * RNG;
        long cap = (long)(E / nb) + (long)(E / nb) / 16 + 640;   // mean + ~13 sigma
        cap = (cap + 63) & ~63L;
        if (cap > 131072) cap = 131072;

        size_t need = 2048 + 64 + (size_t)n * 4
                    + (size_t)CH_S * npad * 4 + (size_t)OVF7 * 4 + (size_t)OVF7 * 8
                    + (size_t)n * 32 + (size_t)nb * cap * 4 + (size_t)nb * cap * 2
                    + (size_t)CHA * npad * 32;

        if (ws_size >= need) {
            char* p = (char*)d_ws;
            unsigned long long* gcur = (unsigned long long*)p;  p += 2048;
            unsigned* ovfc     = (unsigned*)p;   p += 64;
            unsigned* loopcnt  = (unsigned*)p;   p += (size_t)n * 4;
            unsigned* outcnt_c = (unsigned*)p;   p += (size_t)CH_S * npad * 4;
            unsigned* ovf_s    = (unsigned*)p;   p += (size_t)OVF7 * 4;
            unsigned* ovf_d    = (unsigned*)p;   p += (size_t)OVF7 * 8;
            float*    feat     = (float*)p;      p += (size_t)n * 32;
            unsigned* dstpart  = (unsigned*)p;   p += (size_t)nb * cap * 4;
            unsigned short* srcpart = (unsigned short*)p;  p += (size_t)nb * cap * 2;
            float*    accf_c   = (float*)p;

            init7_kernel<<<(n + 255) / 256, 256, 0, stream>>>(gcur, loopcnt, ovfc, nb,
                                                              (int)cap, n);
            part7_kernel<<<NBLK, 256, 0, stream>>>(src, dst, gcur, dstpart, srcpart,
                                                   loopcnt, ovfc, ovf_d, ovf_s,
                                                   E, nb, (int)cap);
            srccount_kernel<<<nb * CH_S, 256, 0, stream>>>(gcur, srcpart, outcnt_c,
                                                           (int)cap, (int)npad, CH_S);
            ovf_s9_kernel<<<64, 256, 0, stream>>>(ovfc, ovf_s, outcnt_c);
            feat_kernel9<<<2048, 256, 0, stream>>>(h, W, outcnt_c, loopcnt, feat,
                                                   n, (int)npad);
            accum3_kernel<<<nb * CHA, 512, 0, stream>>>(gcur, dstpart, feat, accf_c,
                                                        ovfc, ovf_d, (int)cap, (int)npad, CHA);
            ovf_d7_kernel<<<64, 256, 0, stream>>>(ovfc, ovf_d, feat, accf_c);
            final7_kernel<<<(n + 255) / 256, 256, 0, stream>>>(accf_c, feat, loopcnt, b,
                                                               out, n, (int)npad);
            return;
        }
    }

    // ---------------- secondary: round-1 bucket path ----------------
    size_t fixed = (size_t)n * 4 * 2 + 64 + (size_t)n * 8 * 4 + (size_t)OVF_CAP * 8;
    int cap = 0;
    if (ws_size > fixed) cap = (int)((ws_size - fixed) / ((size_t)n * 4));
    if (cap > 96) cap = 96;

    if (cap >= 64) {
        unsigned* cursor = (unsigned*)d_ws;
        unsigned* outcnt = cursor + n;
        unsigned* ovfcnt = outcnt + n;
        float*    feat   = (float*)(ovfcnt + 16);
        unsigned* ovf    = (unsigned*)(feat + (size_t)n * 8);
        unsigned* bucket = ovf + (size_t)OVF_CAP * 2;

        hipMemsetAsync(d_ws, 0, (size_t)n * 8 + 64, stream);

        count_scatter_kernel<<<4096, 256, 0, stream>>>(src, dst, cursor, outcnt, bucket,
                                                       ovfcnt, ovf, E, cap);
        feat_kernel2<<<2048, 256, 0, stream>>>(h, W, outcnt, feat, n);
        gather_kernel<<<((size_t)n * 8 + 255) / 256, 256, 0, stream>>>(cursor, bucket, feat,
                                                                       b, out, n, cap);
        ovf_kernel<<<16, 256, 0, stream>>>(ovfcnt, ovf, feat, cursor, out);
        return;
    }
}